// Round 6
// baseline (574.042 us; speedup 1.0000x reference)
//
#include <hip/hip_runtime.h>

// PoolHiddenNet round 14: r13 ("pool_flip8") with the compile error fixed --
// slot_emb helper was declared after use; inlined as (ce&3)^swz.
// Structure: r12's A-in-LDS/B-from-L2 widened to 512-thread blocks
// (64 rows x ALL 512 cols, 8 waves).
// r12 post-mortem: 195us with MFMA/VALU/HBM all <15% busy = latency-starved
// at 8 waves/CU (2 blocks x 4 waves). Throughput floors (MFMA ~8us, B-L2
// ~30us, A-stream ~50-70us) are all far below 195 -- TLP is the deficit.
// This round: same per-wave K-loop (4 ds_read_b128 + 4 L2 B loads dist-2 +
// 16 MFMA, zero in-loop conversion), but:
//  - block = 64 rows x 512 cols, 8 waves => 2 blocks/CU = 16 waves/CU
//    (LDS 2x80KB = exactly 160KB; __launch_bounds__(512,4) caps VGPR at 128).
//  - A converted once per row-chunk (1600 blocks): demand 420->210 MB.
//  - conversion phase spread over 512 threads (halved latency).
//  - conversion of one block overlaps the K-loop of its CU co-resident.

typedef __bf16 bf16x8 __attribute__((ext_vector_type(8)));
typedef float floatx4 __attribute__((ext_vector_type(4)));

constexpr int NR = 102400;
constexpr int NG = 2048;
constexpr int E  = 128;
constexpr int H  = 512;
constexpr int KD = 640;
constexpr int BM = 128, BN = 128, BK = 32;   // fallback tile
constexpr int NKT = KD / BK;   // 20
constexpr int KH  = H / BK;    // 16: first emb k-tile

__device__ inline unsigned short f2bf(float f) {
    unsigned u = __float_as_uint(f);
    u += 0x7FFF + ((u >> 16) & 1u);   // RNE (finite inputs)
    return (unsigned short)(u >> 16);
}

// pack two fp32 -> bf16x2, round-half-up: 2x v_add + 1x v_perm_b32
__device__ inline unsigned pk2(float lo, float hi) {
    return __builtin_amdgcn_perm(__float_as_uint(hi) + 0x8000u,
                                 __float_as_uint(lo) + 0x8000u, 0x07060302u);
}

// ---------------- prep: segArr + relA (400 blocks) + WmT transpose (80) ----------------
__global__ __launch_bounds__(256) void prep3(
    const float* __restrict__ pos, const int* __restrict__ sse,
    const float* __restrict__ Wm, unsigned short* __restrict__ WmT,
    int* __restrict__ segArr, float* __restrict__ relA)
{
    const int b = blockIdx.x;
    const int t = threadIdx.x;
    __shared__ float tile[64][65];
    if (b < 400) {
        if (!segArr) return;
        const int i = b * 256 + t;
        int l = 0, r = NG + 1;
        while (l < r) { int m = (l + r) >> 1; if (sse[m] <= i) l = m + 1; else r = m; }
        const int g = l - 1;
        segArr[i] = g;
        const int a = sse[g];
        relA[2 * i + 0] = pos[2 * i + 0] - pos[2 * a + 0];
        relA[2 * i + 1] = pos[2 * i + 1] - pos[2 * a + 1];
    } else {
        const int bb = b - 400;             // [0,80): Wm (640x512) -> WmT (512x640) bf16
        const int kb = (bb % 10) * 64, nb = (bb / 10) * 64;
        const int tx = t & 63, tq = t >> 6;
#pragma unroll
        for (int i = 0; i < 16; ++i) {
            const int k = tq * 16 + i;
            tile[k][tx] = Wm[(size_t)(kb + k) * H + nb + tx];
        }
        __syncthreads();
#pragma unroll
        for (int i = 0; i < 16; ++i) {
            const int n = tq * 16 + i;
            WmT[(size_t)(nb + n) * KD + kb + tx] = f2bf(tile[tx][n]);
        }
    }
}

// ---------------- main: 64 rows x 512 cols, 8 waves, A-LDS full-K, B-L2 ----------------
__global__ __launch_bounds__(512, 4) void pool_flip8(
    const float* __restrict__ hist_enc,       // (NR, 512) fp32
    const int*   __restrict__ sse,
    const int*   __restrict__ segArr,         // (NR,)
    const float* __restrict__ relA,           // (NR, 2) fp32
    const float* __restrict__ Ws,             // (2, 128)
    const float* __restrict__ bs,             // (128,)
    const unsigned short* __restrict__ WmT,   // (512, 640) bf16
    const float* __restrict__ bm,             // (512,)
    float*       __restrict__ out)            // (2048, 512) fp32, zeroed
{
    // A panel: 20 k-tiles x 64 rows x 32 k bf16 (r12-proven layout, XOR slot
    // keyed on row). 81920 B; 2 blocks/CU = 160 KB exactly.
    __shared__ __attribute__((aligned(16))) unsigned short As[NKT * 64 * 32];

    const int t   = threadIdx.x;
    const int bid = blockIdx.x;          // [0,1600): one 64-row chunk each
    const int rowBase = bid * 64;

    const int lane  = t & 63;
    const int wv    = t >> 6;            // 8 waves; wave owns 64 rows x 64 cols
    const int lcol  = lane & 15;
    const int lquad = lane >> 4;
    const int cb    = wv * 64;           // this wave's column band (512 cols total)

    // ---- B dist-2 reg prefetch pointers (plain global loads, L2-hot) ----
    const unsigned short* pB[4];
#pragma unroll
    for (int nt = 0; nt < 4; ++nt)
        pB[nt] = WmT + (size_t)(cb + nt * 16 + lcol) * KD + lquad * 8;

    uint4 sB[2][4];
#pragma unroll
    for (int nt = 0; nt < 4; ++nt) {
        sB[0][nt] = *(const uint4*)(pB[nt]);
        sB[1][nt] = *(const uint4*)(pB[nt] + BK);
    }

    // ---- conversion phase: 64 rows x 640 K -> As, spread over 512 threads ----
    // thread t: row t>>3, 8-elem chunk lane phys=t&7; 8 hist passes + 2 emb.
    {
        const int row  = t >> 3;
        const int phys = t & 7;
        const int swz  = (row >> 1) & 3;
        const float* src = hist_enc + (size_t)(rowBase + row) * H + phys * 8;
#pragma unroll
        for (int p = 0; p < 8; ++p) {
            const int c8 = p * 8 + phys;              // [0,64)
            const float4 f0 = *(const float4*)(src + p * 64);
            const float4 f1 = *(const float4*)(src + p * 64 + 4);
            uint4 u;
            u.x = pk2(f0.x, f0.y); u.y = pk2(f0.z, f0.w);
            u.z = pk2(f1.x, f1.y); u.w = pk2(f1.z, f1.w);
            const int kt = c8 >> 2, slot = (c8 & 3) ^ swz;
            *(uint4*)&As[kt * 2048 + row * 32 + slot * 8] = u;
        }
        // emb chunks: relu(rel @ Ws + bs), Ws/bs L1-resident
        const float2 rr = *(const float2*)&relA[2 * (size_t)(rowBase + row)];
#pragma unroll
        for (int p = 0; p < 2; ++p) {
            const int ce = p * 8 + phys;              // [0,16)
            const int e0 = ce * 8;                    // [0,128)
            const float4 w0a = *(const float4*)&Ws[e0];
            const float4 w0b = *(const float4*)&Ws[e0 + 4];
            const float4 w1a = *(const float4*)&Ws[E + e0];
            const float4 w1b = *(const float4*)&Ws[E + e0 + 4];
            const float4 ba4 = *(const float4*)&bs[e0];
            const float4 bb4 = *(const float4*)&bs[e0 + 4];
            float4 fa, fb;
            fa.x = fmaxf(rr.x * w0a.x + rr.y * w1a.x + ba4.x, 0.f);
            fa.y = fmaxf(rr.x * w0a.y + rr.y * w1a.y + ba4.y, 0.f);
            fa.z = fmaxf(rr.x * w0a.z + rr.y * w1a.z + ba4.z, 0.f);
            fa.w = fmaxf(rr.x * w0a.w + rr.y * w1a.w + ba4.w, 0.f);
            fb.x = fmaxf(rr.x * w0b.x + rr.y * w1b.x + bb4.x, 0.f);
            fb.y = fmaxf(rr.x * w0b.y + rr.y * w1b.y + bb4.y, 0.f);
            fb.z = fmaxf(rr.x * w0b.z + rr.y * w1b.z + bb4.z, 0.f);
            fb.w = fmaxf(rr.x * w0b.w + rr.y * w1b.w + bb4.w, 0.f);
            uint4 u;
            u.x = pk2(fa.x, fa.y); u.y = pk2(fa.z, fa.w);
            u.z = pk2(fb.x, fb.y); u.w = pk2(fb.z, fb.w);
            const int slot = (ce & 3) ^ swz;          // same XOR algebra as hist
            *(uint4*)&As[(16 + (ce >> 2)) * 2048 + row * 32 + slot * 8] = u;
        }
    }

    // per-lane epilogue constants (loads overlap conversion)
    float bias[4];
#pragma unroll
    for (int nt = 0; nt < 4; ++nt) bias[nt] = bm[cb + nt * 16 + lcol];
    const int s0 = segArr[rowBase];               // block-uniform
    const int bA = sse[s0 + 1];
    const int bB = (s0 + 2 <= NG) ? sse[s0 + 2] : 0x7fffffff;

    __syncthreads();   // the ONLY barrier: As visible to all waves

    floatx4 acc[4][4];
#pragma unroll
    for (int m = 0; m < 4; ++m)
#pragma unroll
        for (int n = 0; n < 4; ++n) acc[m][n] = (floatx4){0.f, 0.f, 0.f, 0.f};

    // ---- barrier-free K loop: 4 ds_read + dist-2 B refill + 16 MFMA ----
#pragma unroll
    for (int kt = 0; kt < NKT; ++kt) {
        bf16x8 af[4];
#pragma unroll
        for (int mt = 0; mt < 4; ++mt) {
            const int R  = mt * 16 + lcol;
            const int pc = lquad ^ ((R >> 1) & 3);
            af[mt] = *(const bf16x8*)&As[kt * 2048 + R * 32 + pc * 8];
        }
        bf16x8 bfr[4];
#pragma unroll
        for (int nt = 0; nt < 4; ++nt) {
            union { uint4 u; bf16x8 v; } c; c.u = sB[kt & 1][nt];
            bfr[nt] = c.v;
        }
        // refill the freed stage for kt+2 BEFORE the MFMA cluster: the MFMA
        // block + next iteration's front end covers the L2 latency.
        if (kt + 2 < NKT) {
#pragma unroll
            for (int nt = 0; nt < 4; ++nt)
                sB[kt & 1][nt] = *(const uint4*)(pB[nt] + (kt + 2) * BK);
        }

        __builtin_amdgcn_s_setprio(1);
#pragma unroll
        for (int mt = 0; mt < 4; ++mt)
#pragma unroll
            for (int nt = 0; nt < 4; ++nt)
                acc[mt][nt] = __builtin_amdgcn_mfma_f32_16x16x32_bf16(af[mt], bfr[nt], acc[mt][nt], 0, 0, 0);
        __builtin_amdgcn_s_setprio(0);
    }

    // ---- epilogue: per-wave reg reduce + global atomicMax (r11/r12-proven) ----
    float pm0[4] = {0.f, 0.f, 0.f, 0.f};
    float pm1[4] = {0.f, 0.f, 0.f, 0.f};
    float pm2[4] = {0.f, 0.f, 0.f, 0.f};
#pragma unroll
    for (int nt = 0; nt < 4; ++nt) {
#pragma unroll
        for (int mt = 0; mt < 4; ++mt) {
#pragma unroll
            for (int rr = 0; rr < 4; ++rr) {
                const int rowAbs = rowBase + mt * 16 + lquad * 4 + rr;
                const float v = fmaxf(acc[mt][nt][rr] + bias[nt], 0.f);
                const bool geA = rowAbs >= bA;
                const bool geB = rowAbs >= bB;
                pm0[nt] = fmaxf(pm0[nt], (!geA)        ? v : 0.f);
                pm1[nt] = fmaxf(pm1[nt], (geA && !geB) ? v : 0.f);
                pm2[nt] = fmaxf(pm2[nt], (geB)         ? v : 0.f);
            }
        }
    }
#pragma unroll
    for (int s = 0; s < 3; ++s) {
#pragma unroll
        for (int nt = 0; nt < 4; ++nt) {
            float v = (s == 0) ? pm0[nt] : (s == 1) ? pm1[nt] : pm2[nt];
            v = fmaxf(v, __shfl_xor(v, 16));
            v = fmaxf(v, __shfl_xor(v, 32));
            if (lquad == 0 && v > 0.f) {
                float* dst = &out[(size_t)(s0 + s) * H + cb + nt * 16 + lcol];
                atomicMax((int*)dst, __float_as_int(v));
            }
        }
    }
}

// ---------------- fallback (round-2 kernel; only if ws too small) ----------------
constexpr int LDAF = 40;
__global__ __launch_bounds__(256) void pool_mfma_fb(
    const float* __restrict__ hist_enc, const float* __restrict__ pos,
    const int* __restrict__ sse, const float* __restrict__ Ws,
    const float* __restrict__ bs, const unsigned short* __restrict__ WmT,
    const float* __restrict__ bm, float* __restrict__ out)
{
    __shared__ __attribute__((aligned(16))) unsigned short Asf[BM][LDAF];
    __shared__ __attribute__((aligned(16))) unsigned short Bsb[BN][LDAF];
    __shared__ float relRow[BM][2];
    __shared__ int   segRow[BM];
    __shared__ int   bnd[3];
    __shared__ int   Pmax[4][BN + 4];

    const int t = threadIdx.x;
    const int cTile = blockIdx.x * BN;
    const int rowBase = blockIdx.y * BM;

    if (t < BM) {
        const int i = rowBase + t;
        int l = 0, r = NG + 1;
        while (l < r) { int m = (l + r) >> 1; if (sse[m] <= i) l = m + 1; else r = m; }
        const int g = l - 1;
        segRow[t] = g;
        const int a = sse[g];
        relRow[t][0] = pos[2 * i + 0] - pos[2 * a + 0];
        relRow[t][1] = pos[2 * i + 1] - pos[2 * a + 1];
    }
    if (t >= BM && t < BM + 3) bnd[t - BM] = BM;
    for (int idx = t; idx < 4 * (BN + 4); idx += 256) ((int*)Pmax)[idx] = 0;
    __syncthreads();
    if (t < BM - 1) {
        const int s0 = segRow[t], s1 = segRow[t + 1];
        if (s1 != s0) bnd[s1 - segRow[0] - 1] = t + 1;
    }

    const int lane = t & 63, wv = t >> 6;
    const int wr = (wv >> 1) * 64, wc = (wv & 1) * 64;
    const int lcol = lane & 15, lquad = lane >> 4;

    floatx4 acc[4][4];
#pragma unroll
    for (int m = 0; m < 4; ++m)
#pragma unroll
        for (int n = 0; n < 4; ++n) acc[m][n] = (floatx4){0.f, 0.f, 0.f, 0.f};

    for (int kt = 0; kt < KD / BK; ++kt) {
        const int k0 = kt * BK;
        float4 av[4]; uint4 bv[2];
        if (k0 < H) {
#pragma unroll
            for (int i = 0; i < 4; ++i) {
                const int idx = i * 256 + t;
                const int row = idx >> 3, kq = (idx & 7) * 4;
                av[i] = *(const float4*)&hist_enc[(size_t)(rowBase + row) * H + k0 + kq];
            }
        } else {
#pragma unroll
            for (int i = 0; i < 4; ++i) {
                const int idx = i * 256 + t;
                const int row = idx >> 3, kq = (idx & 7) * 4;
                const int e = k0 - H + kq;
                const float4 w0 = *(const float4*)&Ws[e];
                const float4 w1 = *(const float4*)&Ws[E + e];
                const float4 b4 = *(const float4*)&bs[e];
                const float r0 = relRow[row][0], r1 = relRow[row][1];
                av[i].x = fmaxf(r0 * w0.x + r1 * w1.x + b4.x, 0.f);
                av[i].y = fmaxf(r0 * w0.y + r1 * w1.y + b4.y, 0.f);
                av[i].z = fmaxf(r0 * w0.z + r1 * w1.z + b4.z, 0.f);
                av[i].w = fmaxf(r0 * w0.w + r1 * w1.w + b4.w, 0.f);
            }
        }
#pragma unroll
        for (int i = 0; i < 2; ++i) {
            const int idx = i * 256 + t;
            const int n = idx >> 2, q = idx & 3;
            bv[i] = *(const uint4*)&WmT[(size_t)(cTile + n) * KD + k0 + q * 8];
        }
        __syncthreads();
#pragma unroll
        for (int i = 0; i < 4; ++i) {
            const int idx = i * 256 + t;
            const int row = idx >> 3, kq = (idx & 7) * 4;
            ushort4 p;
            p.x = f2bf(av[i].x); p.y = f2bf(av[i].y);
            p.z = f2bf(av[i].z); p.w = f2bf(av[i].w);
            *(ushort4*)&Asf[row][kq] = p;
        }
#pragma unroll
        for (int i = 0; i < 2; ++i) {
            const int idx = i * 256 + t;
            const int n = idx >> 2, q = idx & 3;
            *(uint4*)&Bsb[n][q * 8] = bv[i];
        }
        __syncthreads();

        bf16x8 af[4], bfr[4];
#pragma unroll
        for (int mt = 0; mt < 4; ++mt)
            af[mt] = *(const bf16x8*)&Asf[wr + mt * 16 + lcol][lquad * 8];
#pragma unroll
        for (int nt = 0; nt < 4; ++nt)
            bfr[nt] = *(const bf16x8*)&Bsb[wc + nt * 16 + lcol][lquad * 8];
#pragma unroll
        for (int mt = 0; mt < 4; ++mt)
#pragma unroll
            for (int nt = 0; nt < 4; ++nt)
                acc[mt][nt] = __builtin_amdgcn_mfma_f32_16x16x32_bf16(af[mt], bfr[nt], acc[mt][nt], 0, 0, 0);
    }

    const int b0 = bnd[0], b1 = bnd[1], b2 = bnd[2];
    const int segBase = segRow[0];
#pragma unroll
    for (int nt = 0; nt < 4; ++nt) {
        const int col = wc + nt * 16 + lcol;
        const float bias = bm[cTile + col];
        float pm[4] = {0.f, 0.f, 0.f, 0.f};
#pragma unroll
        for (int mt = 0; mt < 4; ++mt) {
#pragma unroll
            for (int r = 0; r < 4; ++r) {
                const int lr = wr + mt * 16 + lquad * 4 + r;
                const int ls = (lr >= b0) + (lr >= b1) + (lr >= b2);
                const float v = fmaxf(acc[mt][nt][r] + bias, 0.f);
                pm[ls] = fmaxf(pm[ls], v);
            }
        }
#pragma unroll
        for (int ls = 0; ls < 4; ++ls)
            if (pm[ls] > 0.f) atomicMax(&Pmax[ls][col], __float_as_int(pm[ls]));
    }
    __syncthreads();
    for (int idx = t; idx < 4 * BN; idx += 256) {
        const int ls = idx >> 7, col = idx & 127;
        if (ls > 0 && bnd[ls - 1] >= BM) continue;
        const int seg = segBase + ls;
        const int v = Pmax[ls][col];
        const int gs = sse[seg], ge = sse[seg + 1];
        float* dst = &out[(size_t)seg * H + cTile + col];
        if (gs >= rowBase && ge <= rowBase + BM) *dst = __int_as_float(v);
        else atomicMax((int*)dst, v);
    }
}

extern "C" void kernel_launch(void* const* d_in, const int* in_sizes, int n_in,
                              void* d_out, int out_size, void* d_ws, size_t ws_size,
                              hipStream_t stream) {
    const float* hist_enc = (const float*)d_in[0];
    const float* pos      = (const float*)d_in[1];
    const int*   sse      = (const int*)  d_in[2];
    const float* Ws       = (const float*)d_in[3];
    const float* bs       = (const float*)d_in[4];
    const float* Wm       = (const float*)d_in[5];
    const float* bm       = (const float*)d_in[6];
    float*       out      = (float*)d_out;

    const size_t needWmT = (size_t)H * KD * 2;     // 655,360 B
    const size_t needSeg = (size_t)NR * 4;         // 409,600 B
    const size_t needRel = (size_t)NR * 2 * 4;     // 819,200 B
    unsigned short* WmT  = (unsigned short*)d_ws;
    int*            segA = (int*)  ((char*)d_ws + needWmT);
    float*          relA = (float*)((char*)d_ws + needWmT + needSeg);

    (void)hipMemsetAsync(out, 0, (size_t)out_size * sizeof(float), stream);

    if (ws_size >= needWmT + needSeg + needRel) {
        prep3<<<480, 256, 0, stream>>>(pos, sse, Wm, WmT, segA, relA);
        pool_flip8<<<NR / 64, 512, 0, stream>>>(hist_enc, sse, segA, relA, Ws, bs, WmT, bm, out);
    } else {
        prep3<<<480, 256, 0, stream>>>(pos, sse, Wm, WmT, nullptr, nullptr);
        pool_mfma_fb<<<dim3(H / BN, NR / BM), 256, 0, stream>>>(hist_enc, pos, sse, Ws, bs, WmT, bm, out);
    }
}

// Round 7
// 410.465 us; speedup vs baseline: 1.3985x; 1.3985x over previous
//
#include <hip/hip_runtime.h>

// PoolHiddenNet round 15: "pool_mono" -- one 1024-thread block per 64-row
// chunk; wave tile 64x32 (acc=32 AGPR) sized to FIT the forced <=128-reg/lane
// budget of a 1024-thread block.
// r14 post-mortem: 512-thr flip8 spilled (VGPR_Count=64, WRITE_SIZE 7->425MB
// = scratch traffic ~500MB explains the whole 370us). acc[4][4]=64 AGPR +
// ~66 VGPR loop working set cannot fit 128 total. This round:
//  - 1600 blocks x 1024 thr: 1 block/CU, 16 waves = 4 waves/SIMD (50% occ).
//  - wave = 64 rows x 32 cols: acc[4][2]=32 AGPR; VGPR need ~70 < 96. No spill.
//  - A panel (80KB LDS, full K) converted ONCE per chunk by all 1024 threads
//    (5 uint4 writes each, zero duplication); A demand 210MB total.
//  - B bands per-wave disjoint; B read once/block from L2-hot WmT (640KB);
//    dist-2 reg prefetch (sB[2][2]); zero in-loop conversion VALU.
//  - same proven XOR LDS algebra (0 bank conflicts in r12), reg epilogue.

typedef __bf16 bf16x8 __attribute__((ext_vector_type(8)));
typedef float floatx4 __attribute__((ext_vector_type(4)));

constexpr int NR = 102400;
constexpr int NG = 2048;
constexpr int E  = 128;
constexpr int H  = 512;
constexpr int KD = 640;
constexpr int BM = 128, BN = 128, BK = 32;   // fallback tile
constexpr int NKT = KD / BK;   // 20
constexpr int KH  = H / BK;    // 16: first emb k-tile

__device__ inline unsigned short f2bf(float f) {
    unsigned u = __float_as_uint(f);
    u += 0x7FFF + ((u >> 16) & 1u);   // RNE (finite inputs)
    return (unsigned short)(u >> 16);
}

// pack two fp32 -> bf16x2, round-half-up: 2x v_add + 1x v_perm_b32
__device__ inline unsigned pk2(float lo, float hi) {
    return __builtin_amdgcn_perm(__float_as_uint(hi) + 0x8000u,
                                 __float_as_uint(lo) + 0x8000u, 0x07060302u);
}

// ---------------- prep: segArr + relA (400 blocks) + WmT transpose (80) ----------------
__global__ __launch_bounds__(256) void prep3(
    const float* __restrict__ pos, const int* __restrict__ sse,
    const float* __restrict__ Wm, unsigned short* __restrict__ WmT,
    int* __restrict__ segArr, float* __restrict__ relA)
{
    const int b = blockIdx.x;
    const int t = threadIdx.x;
    __shared__ float tile[64][65];
    if (b < 400) {
        if (!segArr) return;
        const int i = b * 256 + t;
        int l = 0, r = NG + 1;
        while (l < r) { int m = (l + r) >> 1; if (sse[m] <= i) l = m + 1; else r = m; }
        const int g = l - 1;
        segArr[i] = g;
        const int a = sse[g];
        relA[2 * i + 0] = pos[2 * i + 0] - pos[2 * a + 0];
        relA[2 * i + 1] = pos[2 * i + 1] - pos[2 * a + 1];
    } else {
        const int bb = b - 400;             // [0,80): Wm (640x512) -> WmT (512x640) bf16
        const int kb = (bb % 10) * 64, nb = (bb / 10) * 64;
        const int tx = t & 63, tq = t >> 6;
#pragma unroll
        for (int i = 0; i < 16; ++i) {
            const int k = tq * 16 + i;
            tile[k][tx] = Wm[(size_t)(kb + k) * H + nb + tx];
        }
        __syncthreads();
#pragma unroll
        for (int i = 0; i < 16; ++i) {
            const int n = tq * 16 + i;
            WmT[(size_t)(nb + n) * KD + kb + tx] = f2bf(tile[tx][n]);
        }
    }
}

// ---------------- main: 64 rows x 512 cols, 16 waves of 64x32, A-LDS, B-L2 ----------------
__global__ __launch_bounds__(1024) void pool_mono(
    const float* __restrict__ hist_enc,       // (NR, 512) fp32
    const int*   __restrict__ sse,
    const int*   __restrict__ segArr,         // (NR,)
    const float* __restrict__ relA,           // (NR, 2) fp32
    const float* __restrict__ Ws,             // (2, 128)
    const float* __restrict__ bs,             // (128,)
    const unsigned short* __restrict__ WmT,   // (512, 640) bf16
    const float* __restrict__ bm,             // (512,)
    float*       __restrict__ out)            // (2048, 512) fp32, zeroed
{
    // A panel: 20 k-tiles x 64 rows x 32 k bf16 (r12-proven layout, XOR slot
    // keyed on row). 81920 B; 1 block/CU.
    __shared__ __attribute__((aligned(16))) unsigned short As[NKT * 64 * 32];

    const int t   = threadIdx.x;
    const int bid = blockIdx.x;          // [0,1600): one 64-row chunk each
    const int rowBase = bid * 64;

    const int lane  = t & 63;
    const int wv    = t >> 6;            // 16 waves; wave owns 64 rows x 32 cols
    const int lcol  = lane & 15;
    const int lquad = lane >> 4;
    const int cb    = wv * 32;           // this wave's column band (512 cols total)

    // ---- B dist-2 reg prefetch pointers (plain global loads, L2-hot) ----
    const unsigned short* pB[2];
#pragma unroll
    for (int nt = 0; nt < 2; ++nt)
        pB[nt] = WmT + (size_t)(cb + nt * 16 + lcol) * KD + lquad * 8;

    uint4 sB[2][2];
#pragma unroll
    for (int nt = 0; nt < 2; ++nt) {
        sB[0][nt] = *(const uint4*)(pB[nt]);
        sB[1][nt] = *(const uint4*)(pB[nt] + BK);
    }

    // ---- conversion phase: 64 rows x 640 K -> As, spread over 1024 threads ----
    // thread t: row t>>4, chunk lane phys=t&15; 4 hist passes + 1 emb. Each
    // thread writes exactly 5 uint4 -> 80KB total, zero duplication.
    {
        const int row  = t >> 4;
        const int phys = t & 15;
        const int swz  = (row >> 1) & 3;
        const int slot = (phys & 3) ^ swz;
        const float* src = hist_enc + (size_t)(rowBase + row) * H + phys * 8;
#pragma unroll
        for (int p = 0; p < 4; ++p) {
            const int c8 = p * 16 + phys;             // [0,64)
            const float4 f0 = *(const float4*)(src + p * 128);
            const float4 f1 = *(const float4*)(src + p * 128 + 4);
            uint4 u;
            u.x = pk2(f0.x, f0.y); u.y = pk2(f0.z, f0.w);
            u.z = pk2(f1.x, f1.y); u.w = pk2(f1.z, f1.w);
            const int kt = c8 >> 2;
            *(uint4*)&As[kt * 2048 + row * 32 + slot * 8] = u;
        }
        // emb chunk: ce = phys in [0,16), relu(rel @ Ws + bs)
        {
            const float2 rr = *(const float2*)&relA[2 * (size_t)(rowBase + row)];
            const int e0 = phys * 8;                  // [0,128)
            const float4 w0a = *(const float4*)&Ws[e0];
            const float4 w0b = *(const float4*)&Ws[e0 + 4];
            const float4 w1a = *(const float4*)&Ws[E + e0];
            const float4 w1b = *(const float4*)&Ws[E + e0 + 4];
            const float4 ba4 = *(const float4*)&bs[e0];
            const float4 bb4 = *(const float4*)&bs[e0 + 4];
            float4 fa, fb;
            fa.x = fmaxf(rr.x * w0a.x + rr.y * w1a.x + ba4.x, 0.f);
            fa.y = fmaxf(rr.x * w0a.y + rr.y * w1a.y + ba4.y, 0.f);
            fa.z = fmaxf(rr.x * w0a.z + rr.y * w1a.z + ba4.z, 0.f);
            fa.w = fmaxf(rr.x * w0a.w + rr.y * w1a.w + ba4.w, 0.f);
            fb.x = fmaxf(rr.x * w0b.x + rr.y * w1b.x + bb4.x, 0.f);
            fb.y = fmaxf(rr.x * w0b.y + rr.y * w1b.y + bb4.y, 0.f);
            fb.z = fmaxf(rr.x * w0b.z + rr.y * w1b.z + bb4.z, 0.f);
            fb.w = fmaxf(rr.x * w0b.w + rr.y * w1b.w + bb4.w, 0.f);
            uint4 u;
            u.x = pk2(fa.x, fa.y); u.y = pk2(fa.z, fa.w);
            u.z = pk2(fb.x, fb.y); u.w = pk2(fb.z, fb.w);
            const int kt = 16 + (phys >> 2);
            *(uint4*)&As[kt * 2048 + row * 32 + slot * 8] = u;
        }
    }

    // per-lane epilogue constants (loads overlap conversion)
    float bias[2];
#pragma unroll
    for (int nt = 0; nt < 2; ++nt) bias[nt] = bm[cb + nt * 16 + lcol];
    const int s0 = segArr[rowBase];               // block-uniform
    const int bA = sse[s0 + 1];
    const int bB = (s0 + 2 <= NG) ? sse[s0 + 2] : 0x7fffffff;

    __syncthreads();   // the ONLY barrier: As visible to all waves

    floatx4 acc[4][2];
#pragma unroll
    for (int m = 0; m < 4; ++m)
#pragma unroll
        for (int n = 0; n < 2; ++n) acc[m][n] = (floatx4){0.f, 0.f, 0.f, 0.f};

    // ---- barrier-free K loop: 4 ds_read + dist-2 B refill + 8 MFMA ----
#pragma unroll
    for (int kt = 0; kt < NKT; ++kt) {
        bf16x8 af[4];
#pragma unroll
        for (int mt = 0; mt < 4; ++mt) {
            const int R  = mt * 16 + lcol;
            const int pc = lquad ^ ((R >> 1) & 3);
            af[mt] = *(const bf16x8*)&As[kt * 2048 + R * 32 + pc * 8];
        }
        bf16x8 bfr[2];
#pragma unroll
        for (int nt = 0; nt < 2; ++nt) {
            union { uint4 u; bf16x8 v; } c; c.u = sB[kt & 1][nt];
            bfr[nt] = c.v;
        }
        // refill the freed stage for kt+2 (MFMA block + next iter front end
        // covers the L2 latency; counted vmcnt, no barrier drain)
        if (kt + 2 < NKT) {
#pragma unroll
            for (int nt = 0; nt < 2; ++nt)
                sB[kt & 1][nt] = *(const uint4*)(pB[nt] + (kt + 2) * BK);
        }

        __builtin_amdgcn_s_setprio(1);
#pragma unroll
        for (int mt = 0; mt < 4; ++mt)
#pragma unroll
            for (int nt = 0; nt < 2; ++nt)
                acc[mt][nt] = __builtin_amdgcn_mfma_f32_16x16x32_bf16(af[mt], bfr[nt], acc[mt][nt], 0, 0, 0);
        __builtin_amdgcn_s_setprio(0);
    }

    // ---- epilogue: per-wave reg reduce + global atomicMax (r11/r12-proven) ----
    float pm0[2] = {0.f, 0.f};
    float pm1[2] = {0.f, 0.f};
    float pm2[2] = {0.f, 0.f};
#pragma unroll
    for (int nt = 0; nt < 2; ++nt) {
#pragma unroll
        for (int mt = 0; mt < 4; ++mt) {
#pragma unroll
            for (int rr = 0; rr < 4; ++rr) {
                const int rowAbs = rowBase + mt * 16 + lquad * 4 + rr;
                const float v = fmaxf(acc[mt][nt][rr] + bias[nt], 0.f);
                const bool geA = rowAbs >= bA;
                const bool geB = rowAbs >= bB;
                pm0[nt] = fmaxf(pm0[nt], (!geA)        ? v : 0.f);
                pm1[nt] = fmaxf(pm1[nt], (geA && !geB) ? v : 0.f);
                pm2[nt] = fmaxf(pm2[nt], (geB)         ? v : 0.f);
            }
        }
    }
#pragma unroll
    for (int s = 0; s < 3; ++s) {
#pragma unroll
        for (int nt = 0; nt < 2; ++nt) {
            float v = (s == 0) ? pm0[nt] : (s == 1) ? pm1[nt] : pm2[nt];
            v = fmaxf(v, __shfl_xor(v, 16));
            v = fmaxf(v, __shfl_xor(v, 32));
            if (lquad == 0 && v > 0.f) {
                float* dst = &out[(size_t)(s0 + s) * H + cb + nt * 16 + lcol];
                atomicMax((int*)dst, __float_as_int(v));
            }
        }
    }
}

// ---------------- fallback (round-2 kernel; only if ws too small) ----------------
constexpr int LDAF = 40;
__global__ __launch_bounds__(256) void pool_mfma_fb(
    const float* __restrict__ hist_enc, const float* __restrict__ pos,
    const int* __restrict__ sse, const float* __restrict__ Ws,
    const float* __restrict__ bs, const unsigned short* __restrict__ WmT,
    const float* __restrict__ bm, float* __restrict__ out)
{
    __shared__ __attribute__((aligned(16))) unsigned short Asf[BM][LDAF];
    __shared__ __attribute__((aligned(16))) unsigned short Bsb[BN][LDAF];
    __shared__ float relRow[BM][2];
    __shared__ int   segRow[BM];
    __shared__ int   bnd[3];
    __shared__ int   Pmax[4][BN + 4];

    const int t = threadIdx.x;
    const int cTile = blockIdx.x * BN;
    const int rowBase = blockIdx.y * BM;

    if (t < BM) {
        const int i = rowBase + t;
        int l = 0, r = NG + 1;
        while (l < r) { int m = (l + r) >> 1; if (sse[m] <= i) l = m + 1; else r = m; }
        const int g = l - 1;
        segRow[t] = g;
        const int a = sse[g];
        relRow[t][0] = pos[2 * i + 0] - pos[2 * a + 0];
        relRow[t][1] = pos[2 * i + 1] - pos[2 * a + 1];
    }
    if (t >= BM && t < BM + 3) bnd[t - BM] = BM;
    for (int idx = t; idx < 4 * (BN + 4); idx += 256) ((int*)Pmax)[idx] = 0;
    __syncthreads();
    if (t < BM - 1) {
        const int s0 = segRow[t], s1 = segRow[t + 1];
        if (s1 != s0) bnd[s1 - segRow[0] - 1] = t + 1;
    }

    const int lane = t & 63, wv = t >> 6;
    const int wr = (wv >> 1) * 64, wc = (wv & 1) * 64;
    const int lcol = lane & 15, lquad = lane >> 4;

    floatx4 acc[4][4];
#pragma unroll
    for (int m = 0; m < 4; ++m)
#pragma unroll
        for (int n = 0; n < 4; ++n) acc[m][n] = (floatx4){0.f, 0.f, 0.f, 0.f};

    for (int kt = 0; kt < KD / BK; ++kt) {
        const int k0 = kt * BK;
        float4 av[4]; uint4 bv[2];
        if (k0 < H) {
#pragma unroll
            for (int i = 0; i < 4; ++i) {
                const int idx = i * 256 + t;
                const int row = idx >> 3, kq = (idx & 7) * 4;
                av[i] = *(const float4*)&hist_enc[(size_t)(rowBase + row) * H + k0 + kq];
            }
        } else {
#pragma unroll
            for (int i = 0; i < 4; ++i) {
                const int idx = i * 256 + t;
                const int row = idx >> 3, kq = (idx & 7) * 4;
                const int e = k0 - H + kq;
                const float4 w0 = *(const float4*)&Ws[e];
                const float4 w1 = *(const float4*)&Ws[E + e];
                const float4 b4 = *(const float4*)&bs[e];
                const float r0 = relRow[row][0], r1 = relRow[row][1];
                av[i].x = fmaxf(r0 * w0.x + r1 * w1.x + b4.x, 0.f);
                av[i].y = fmaxf(r0 * w0.y + r1 * w1.y + b4.y, 0.f);
                av[i].z = fmaxf(r0 * w0.z + r1 * w1.z + b4.z, 0.f);
                av[i].w = fmaxf(r0 * w0.w + r1 * w1.w + b4.w, 0.f);
            }
        }
#pragma unroll
        for (int i = 0; i < 2; ++i) {
            const int idx = i * 256 + t;
            const int n = idx >> 2, q = idx & 3;
            bv[i] = *(const uint4*)&WmT[(size_t)(cTile + n) * KD + k0 + q * 8];
        }
        __syncthreads();
#pragma unroll
        for (int i = 0; i < 4; ++i) {
            const int idx = i * 256 + t;
            const int row = idx >> 3, kq = (idx & 7) * 4;
            ushort4 p;
            p.x = f2bf(av[i].x); p.y = f2bf(av[i].y);
            p.z = f2bf(av[i].z); p.w = f2bf(av[i].w);
            *(ushort4*)&Asf[row][kq] = p;
        }
#pragma unroll
        for (int i = 0; i < 2; ++i) {
            const int idx = i * 256 + t;
            const int n = idx >> 2, q = idx & 3;
            *(uint4*)&Bsb[n][q * 8] = bv[i];
        }
        __syncthreads();

        bf16x8 af[4], bfr[4];
#pragma unroll
        for (int mt = 0; mt < 4; ++mt)
            af[mt] = *(const bf16x8*)&Asf[wr + mt * 16 + lcol][lquad * 8];
#pragma unroll
        for (int nt = 0; nt < 4; ++nt)
            bfr[nt] = *(const bf16x8*)&Bsb[wc + nt * 16 + lcol][lquad * 8];
#pragma unroll
        for (int mt = 0; mt < 4; ++mt)
#pragma unroll
            for (int nt = 0; nt < 4; ++nt)
                acc[mt][nt] = __builtin_amdgcn_mfma_f32_16x16x32_bf16(af[mt], bfr[nt], acc[mt][nt], 0, 0, 0);
    }

    const int b0 = bnd[0], b1 = bnd[1], b2 = bnd[2];
    const int segBase = segRow[0];
#pragma unroll
    for (int nt = 0; nt < 4; ++nt) {
        const int col = wc + nt * 16 + lcol;
        const float bias = bm[cTile + col];
        float pm[4] = {0.f, 0.f, 0.f, 0.f};
#pragma unroll
        for (int mt = 0; mt < 4; ++mt) {
#pragma unroll
            for (int r = 0; r < 4; ++r) {
                const int lr = wr + mt * 16 + lquad * 4 + r;
                const int ls = (lr >= b0) + (lr >= b1) + (lr >= b2);
                const float v = fmaxf(acc[mt][nt][r] + bias, 0.f);
                pm[ls] = fmaxf(pm[ls], v);
            }
        }
#pragma unroll
        for (int ls = 0; ls < 4; ++ls)
            if (pm[ls] > 0.f) atomicMax(&Pmax[ls][col], __float_as_int(pm[ls]));
    }
    __syncthreads();
    for (int idx = t; idx < 4 * BN; idx += 256) {
        const int ls = idx >> 7, col = idx & 127;
        if (ls > 0 && bnd[ls - 1] >= BM) continue;
        const int seg = segBase + ls;
        const int v = Pmax[ls][col];
        const int gs = sse[seg], ge = sse[seg + 1];
        float* dst = &out[(size_t)seg * H + cTile + col];
        if (gs >= rowBase && ge <= rowBase + BM) *dst = __int_as_float(v);
        else atomicMax((int*)dst, v);
    }
}

extern "C" void kernel_launch(void* const* d_in, const int* in_sizes, int n_in,
                              void* d_out, int out_size, void* d_ws, size_t ws_size,
                              hipStream_t stream) {
    const float* hist_enc = (const float*)d_in[0];
    const float* pos      = (const float*)d_in[1];
    const int*   sse      = (const int*)  d_in[2];
    const float* Ws       = (const float*)d_in[3];
    const float* bs       = (const float*)d_in[4];
    const float* Wm       = (const float*)d_in[5];
    const float* bm       = (const float*)d_in[6];
    float*       out      = (float*)d_out;

    const size_t needWmT = (size_t)H * KD * 2;     // 655,360 B
    const size_t needSeg = (size_t)NR * 4;         // 409,600 B
    const size_t needRel = (size_t)NR * 2 * 4;     // 819,200 B
    unsigned short* WmT  = (unsigned short*)d_ws;
    int*            segA = (int*)  ((char*)d_ws + needWmT);
    float*          relA = (float*)((char*)d_ws + needWmT + needSeg);

    (void)hipMemsetAsync(out, 0, (size_t)out_size * sizeof(float), stream);

    if (ws_size >= needWmT + needSeg + needRel) {
        prep3<<<480, 256, 0, stream>>>(pos, sse, Wm, WmT, segA, relA);
        pool_mono<<<NR / 64, 1024, 0, stream>>>(hist_enc, sse, segA, relA, Ws, bs, WmT, bm, out);
    } else {
        prep3<<<480, 256, 0, stream>>>(pos, sse, Wm, WmT, nullptr, nullptr);
        pool_mfma_fb<<<dim3(H / BN, NR / BM), 256, 0, stream>>>(hist_enc, pos, sse, Ws, bs, WmT, bm, out);
    }
}